// Round 2
// baseline (1059.469 us; speedup 1.0000x reference)
//
#include <hip/hip_runtime.h>
#include <hip/hip_bf16.h>

#define DM   2048
#define LSEQ 2048
#define NB   2
#define NH   16
#define HDIM 128
#define DFF  8192

typedef __attribute__((ext_vector_type(8))) short bf16x8;
typedef __attribute__((ext_vector_type(4))) float f32x4;

typedef __attribute__((address_space(1))) void gvoid;
typedef __attribute__((address_space(3))) void lvoid;
#define GLDS16(g, s) __builtin_amdgcn_global_load_lds((const gvoid*)(g), (lvoid*)(s), 16, 0, 0)

__device__ __forceinline__ unsigned short f2b(float f) {
    __hip_bfloat16 h = __float2bfloat16(f);
    return *reinterpret_cast<unsigned short*>(&h);
}

// ---------------- transpose + fp32->bf16 convert: in[R][C] f32 -> out[C][R] bf16
__global__ __launch_bounds__(256) void transpose_bf16(const float* __restrict__ in,
                                                      unsigned short* __restrict__ out,
                                                      int R, int C) {
    __shared__ float t[32][33];
    const int c0 = blockIdx.x * 32, r0 = blockIdx.y * 32;
    const int tx = threadIdx.x, ty = threadIdx.y;  // block (32,8)
#pragma unroll
    for (int i = 0; i < 4; i++)
        t[ty + 8 * i][tx] = in[(size_t)(r0 + ty + 8 * i) * C + c0 + tx];
    __syncthreads();
#pragma unroll
    for (int i = 0; i < 4; i++)
        out[(size_t)(c0 + ty + 8 * i) * R + r0 + tx] = f2b(t[tx][ty + 8 * i]);
}

// ---------------- LayerNorm: x[row][2048] f32 -> out bf16
__global__ __launch_bounds__(256) void ln_k(const float* __restrict__ x,
                                            const float* __restrict__ g,
                                            const float* __restrict__ bta,
                                            unsigned short* __restrict__ out) {
    const int row = blockIdx.x, tid = threadIdx.x;
    const float* xr = x + (size_t)row * DM;
    float4 v0 = *(const float4*)&xr[tid * 4];
    float4 v1 = *(const float4*)&xr[1024 + tid * 4];
    float s  = v0.x + v0.y + v0.z + v0.w + v1.x + v1.y + v1.z + v1.w;
    float ss = v0.x * v0.x + v0.y * v0.y + v0.z * v0.z + v0.w * v0.w
             + v1.x * v1.x + v1.y * v1.y + v1.z * v1.z + v1.w * v1.w;
#pragma unroll
    for (int o = 32; o; o >>= 1) { s += __shfl_down(s, o); ss += __shfl_down(ss, o); }
    __shared__ float red[8];
    const int w = tid >> 6, l = tid & 63;
    if (l == 0) { red[w] = s; red[4 + w] = ss; }
    __syncthreads();
    s  = red[0] + red[1] + red[2] + red[3];
    ss = red[4] + red[5] + red[6] + red[7];
    const float mu  = s * (1.0f / DM);
    const float var = ss * (1.0f / DM) - mu * mu;
    const float rst = rsqrtf(var + 1e-5f);
    float4 g0 = *(const float4*)&g[tid * 4];
    float4 b0 = *(const float4*)&bta[tid * 4];
    float4 g1 = *(const float4*)&g[1024 + tid * 4];
    float4 b1 = *(const float4*)&bta[1024 + tid * 4];
    ushort4 o0, o1;
    o0.x = f2b((v0.x - mu) * rst * g0.x + b0.x);
    o0.y = f2b((v0.y - mu) * rst * g0.y + b0.y);
    o0.z = f2b((v0.z - mu) * rst * g0.z + b0.z);
    o0.w = f2b((v0.w - mu) * rst * g0.w + b0.w);
    o1.x = f2b((v1.x - mu) * rst * g1.x + b1.x);
    o1.y = f2b((v1.y - mu) * rst * g1.y + b1.y);
    o1.z = f2b((v1.z - mu) * rst * g1.z + b1.z);
    o1.w = f2b((v1.w - mu) * rst * g1.w + b1.w);
    *(ushort4*)&out[(size_t)row * DM + tid * 4] = o0;
    *(ushort4*)&out[(size_t)row * DM + 1024 + tid * 4] = o1;
}

// ---------------- GEMM: C[M][N] = A[M][K]_bf16 @ Bt[N][K]_bf16 (+bias,+gelu,+res)
// m97 structure: 128x128 tile, BK=32, 4 waves * (4x4) 16x16x32 mfma, global_load_lds w=16
template <bool BIAS, bool GELU_, bool RES, bool OUTBF>
__global__ __launch_bounds__(256) void gemm_k(const unsigned short* __restrict__ A,
                                              const unsigned short* __restrict__ Bt,
                                              const float* __restrict__ bias,
                                              const float* __restrict__ res,
                                              void* __restrict__ outp,
                                              int M, int N, int K) {
    __shared__ unsigned short Al[128 * 32];
    __shared__ unsigned short Bl[128 * 32];
    const int tid = threadIdx.x, w = tid >> 6, l = tid & 63;
    const int n0 = blockIdx.x * 128, m0 = blockIdx.y * 128;
    const int wr = (w >> 1) * 64, wc = (w & 1) * 64;
    const int lr = l & 15, ko = (l >> 4) * 8;
    f32x4 acc[4][4] = {};

    const int srow = w * 32 + (l >> 2);
    const int skk  = (l & 3) * 8;
    const unsigned short* ga0 = A + (size_t)(m0 + srow) * K + skk;
    const unsigned short* ga1 = ga0 + (size_t)16 * K;
    const unsigned short* gb0 = Bt + (size_t)(n0 + srow) * K + skk;
    const unsigned short* gb1 = gb0 + (size_t)16 * K;
    unsigned short* la = &Al[w * 1024];
    unsigned short* lb = &Bl[w * 1024];
    const int nk = K >> 5;
    for (int kt = 0; kt < nk; ++kt) {
        GLDS16(ga0, la);
        GLDS16(ga1, la + 512);
        GLDS16(gb0, lb);
        GLDS16(gb1, lb + 512);
        ga0 += 32; ga1 += 32; gb0 += 32; gb1 += 32;
        __syncthreads();
        bf16x8 af[4], bv[4];
#pragma unroll
        for (int i = 0; i < 4; i++) af[i] = *(const bf16x8*)&Al[(wr + i * 16 + lr) * 32 + ko];
#pragma unroll
        for (int i = 0; i < 4; i++) bv[i] = *(const bf16x8*)&Bl[(wc + i * 16 + lr) * 32 + ko];
#pragma unroll
        for (int i = 0; i < 4; i++)
#pragma unroll
            for (int j = 0; j < 4; j++)
                acc[i][j] = __builtin_amdgcn_mfma_f32_16x16x32_bf16(af[i], bv[j], acc[i][j], 0, 0, 0);
        __syncthreads();
    }
    // epilogue: C/D map row=(l>>4)*4+r, col=l&15 (HW-verified)
#pragma unroll
    for (int j = 0; j < 4; j++) {
        const int col = n0 + wc + j * 16 + lr;
        const float bvv = BIAS ? bias[col] : 0.0f;
#pragma unroll
        for (int i = 0; i < 4; i++) {
#pragma unroll
            for (int r = 0; r < 4; r++) {
                const int row = m0 + wr + i * 16 + (l >> 4) * 4 + r;
                float v = acc[i][j][r] + bvv;
                if (GELU_) v = 0.5f * v * (1.0f + erff(v * 0.7071067811865476f));
                if (RES) v += res[(size_t)row * N + col];
                if (OUTBF) ((unsigned short*)outp)[(size_t)row * N + col] = f2b(v);
                else       ((float*)outp)[(size_t)row * N + col] = v;
            }
        }
    }
}

// ---------------- flash attention (causal), qkv bf16 [B*L][3*DM], out bf16 [B*L][DM]
__global__ __launch_bounds__(256) void flash_attn_k(const unsigned short* __restrict__ qkv,
                                                    unsigned short* __restrict__ out) {
    __shared__ unsigned short Kl[64 * 136];   // K tile [key][d], padded
    __shared__ unsigned short Vt[128 * 72];   // V tile transposed [d][key], padded
    __shared__ unsigned short Pl[4][16 * 72]; // per-wave P [qrow][key], padded
    const int tid = threadIdx.x, w = tid >> 6, l = tid & 63;
    const int qt = blockIdx.x, bh = blockIdx.y, b = bh >> 4, h = bh & 15;
    const int q0 = qt * 64, qw = q0 + w * 16;
    const int lr = l & 15, lg = l >> 4;

    bf16x8 qf[4];
    {
        const unsigned short* qb = qkv + (size_t)(b * LSEQ + qw + lr) * (3 * DM) + h * HDIM + lg * 8;
#pragma unroll
        for (int kc = 0; kc < 4; kc++) qf[kc] = *(const bf16x8*)(qb + kc * 32);
    }
    f32x4 O[8] = {};
    float m_run[4] = {-1e30f, -1e30f, -1e30f, -1e30f};
    float l_run[4] = {};
    const float sc = 0.08838834764831845f;  // 1/sqrt(128)

    for (int kt = 0; kt <= qt; ++kt) {
        const int k0 = kt * 64;
        // stage K row-major, V transposed.  64 rows x 128 cols = 1024 x 16B chunks
#pragma unroll
        for (int i = 0; i < 4; i++) {
            const int seg = i * 256 + tid;       // 0..1023
            const int row = seg >> 4;            // 0..63   (16 chunks per row)
            const int c8  = (seg & 15) * 8;      // 0..120
            const unsigned short* src = qkv + (size_t)(b * LSEQ + k0 + row) * (3 * DM) + DM + h * HDIM + c8;
            *(uint4*)&Kl[row * 136 + c8] = *(const uint4*)src;
            unsigned short tmp[8];
            *(uint4*)tmp = *(const uint4*)(src + DM);
#pragma unroll
            for (int j = 0; j < 8; j++) Vt[(c8 + j) * 72 + row] = tmp[j];
        }
        __syncthreads();
        // S = Q K^T  (A=Q rows, B=K^T: lane reads Kl[key=st*16+lr][d])
        f32x4 S[4] = {};
#pragma unroll
        for (int st = 0; st < 4; ++st)
#pragma unroll
            for (int kc = 0; kc < 4; kc++) {
                bf16x8 kb = *(const bf16x8*)&Kl[(st * 16 + lr) * 136 + kc * 32 + lg * 8];
                S[st] = __builtin_amdgcn_mfma_f32_16x16x32_bf16(qf[kc], kb, S[st], 0, 0, 0);
            }
        const bool last = (kt == qt);
#pragma unroll
        for (int r = 0; r < 4; r++) {
            const int row = qw + lg * 4 + r;
            float s0 = S[0][r] * sc, s1 = S[1][r] * sc, s2 = S[2][r] * sc, s3 = S[3][r] * sc;
            if (last) {
                if (k0 +  0 + lr > row) s0 = -1e30f;
                if (k0 + 16 + lr > row) s1 = -1e30f;
                if (k0 + 32 + lr > row) s2 = -1e30f;
                if (k0 + 48 + lr > row) s3 = -1e30f;
            }
            float mt = fmaxf(fmaxf(s0, s1), fmaxf(s2, s3));
            mt = fmaxf(mt, __shfl_xor(mt, 1));
            mt = fmaxf(mt, __shfl_xor(mt, 2));
            mt = fmaxf(mt, __shfl_xor(mt, 4));
            mt = fmaxf(mt, __shfl_xor(mt, 8));
            const float mn = fmaxf(m_run[r], mt);
            const float al = __expf(m_run[r] - mn);
            m_run[r] = mn;
            float p0 = __expf(s0 - mn), p1 = __expf(s1 - mn), p2 = __expf(s2 - mn), p3 = __expf(s3 - mn);
            float ts = p0 + p1 + p2 + p3;
            ts += __shfl_xor(ts, 1);
            ts += __shfl_xor(ts, 2);
            ts += __shfl_xor(ts, 4);
            ts += __shfl_xor(ts, 8);
            l_run[r] = l_run[r] * al + ts;
#pragma unroll
            for (int c = 0; c < 8; c++) O[c][r] *= al;
            unsigned short* pr = &Pl[w][(lg * 4 + r) * 72 + lr];
            pr[0] = f2b(p0); pr[16] = f2b(p1); pr[32] = f2b(p2); pr[48] = f2b(p3);
        }
        // O += P @ V   (A=P[qrow][key], B=V[key][d] read from Vt[d][key])
#pragma unroll
        for (int ks = 0; ks < 2; ++ks) {
            bf16x8 pa = *(const bf16x8*)&Pl[w][lr * 72 + ks * 32 + lg * 8];
#pragma unroll
            for (int c = 0; c < 8; c++) {
                bf16x8 vb = *(const bf16x8*)&Vt[(c * 16 + lr) * 72 + ks * 32 + lg * 8];
                O[c] = __builtin_amdgcn_mfma_f32_16x16x32_bf16(pa, vb, O[c], 0, 0, 0);
            }
        }
        __syncthreads();
    }
#pragma unroll
    for (int r = 0; r < 4; r++) {
        const float inv = 1.0f / l_run[r];
        const size_t ro = (size_t)(b * LSEQ + qw + lg * 4 + r) * DM + h * HDIM;
#pragma unroll
        for (int c = 0; c < 8; c++) out[ro + c * 16 + lr] = f2b(O[c][r] * inv);
    }
}

extern "C" void kernel_launch(void* const* d_in, const int* in_sizes, int n_in,
                              void* d_out, int out_size, void* d_ws, size_t ws_size,
                              hipStream_t stream) {
    const float* x     = (const float*)d_in[0];
    // d_in[1] = attention_mask (causal tril; hardcoded in flash kernel)
    const float* w_qkv = (const float*)d_in[2];
    const float* w_o   = (const float*)d_in[3];
    const float* g1    = (const float*)d_in[4];
    const float* bl1   = (const float*)d_in[5];
    const float* g2    = (const float*)d_in[6];
    const float* bl2   = (const float*)d_in[7];
    const float* w1    = (const float*)d_in[8];
    const float* b1    = (const float*)d_in[9];
    const float* w2    = (const float*)d_in[10];
    const float* b2    = (const float*)d_in[11];
    float* out = (float*)d_out;

    unsigned char* p = (unsigned char*)d_ws;
    unsigned short* wqkvT = (unsigned short*)p; p += (size_t)3 * DM * DM * 2;   // [6144][2048]
    unsigned short* woT   = (unsigned short*)p; p += (size_t)DM * DM * 2;       // [2048][2048]
    unsigned short* w1T   = (unsigned short*)p; p += (size_t)DFF * DM * 2;      // [8192][2048]
    unsigned short* w2T   = (unsigned short*)p; p += (size_t)DM * DFF * 2;      // [2048][8192]
    unsigned short* hbuf  = (unsigned short*)p; p += (size_t)NB * LSEQ * DM * 2;  // h / attn_out / h2
    unsigned short* big   = (unsigned short*)p; p += (size_t)NB * LSEQ * DFF * 2; // qkv then mlp hidden
    float* x2 = out;  // x2 lives in d_out; final GEMM reads it as res then overwrites in place

    const int R = NB * LSEQ;  // 4096
    dim3 tb(32, 8);
    transpose_bf16<<<dim3(3 * DM / 32, DM / 32), tb, 0, stream>>>(w_qkv, wqkvT, DM, 3 * DM);
    transpose_bf16<<<dim3(DM / 32, DM / 32), tb, 0, stream>>>(w_o, woT, DM, DM);
    transpose_bf16<<<dim3(DFF / 32, DM / 32), tb, 0, stream>>>(w1, w1T, DM, DFF);
    transpose_bf16<<<dim3(DM / 32, DFF / 32), tb, 0, stream>>>(w2, w2T, DFF, DM);

    ln_k<<<R, 256, 0, stream>>>(x, g1, bl1, hbuf);
    gemm_k<false, false, false, true><<<dim3(3 * DM / 128, R / 128), 256, 0, stream>>>(
        hbuf, wqkvT, nullptr, nullptr, big, R, 3 * DM, DM);
    flash_attn_k<<<dim3(LSEQ / 64, NB * NH), 256, 0, stream>>>(big, hbuf);
    gemm_k<false, false, true, false><<<dim3(DM / 128, R / 128), 256, 0, stream>>>(
        hbuf, woT, nullptr, x, x2, R, DM, DM);
    ln_k<<<R, 256, 0, stream>>>(x2, g2, bl2, hbuf);
    gemm_k<true, true, false, true><<<dim3(DFF / 128, R / 128), 256, 0, stream>>>(
        hbuf, w1T, b1, nullptr, big, R, DFF, DM);
    gemm_k<true, false, true, false><<<dim3(DM / 128, R / 128), 256, 0, stream>>>(
        big, w2T, b2, x2, out, R, DM, DFF);
}

// Round 3
// 805.895 us; speedup vs baseline: 1.3146x; 1.3146x over previous
//
#include <hip/hip_runtime.h>
#include <hip/hip_bf16.h>

#define DM   2048
#define LSEQ 2048
#define NB   2
#define NH   16
#define HDIM 128
#define DFF  8192

typedef __attribute__((ext_vector_type(8))) short bf16x8;
typedef __attribute__((ext_vector_type(4))) float f32x4;

typedef __attribute__((address_space(1))) void gvoid;
typedef __attribute__((address_space(3))) void lvoid;
#define GLDS16(g, s) __builtin_amdgcn_global_load_lds((const gvoid*)(g), (lvoid*)(s), 16, 0, 0)

__device__ __forceinline__ unsigned short f2b(float f) {
    __hip_bfloat16 h = __float2bfloat16(f);
    return *reinterpret_cast<unsigned short*>(&h);
}

// ---------------- transpose + fp32->bf16 convert: in[R][C] f32 -> out[C][R] bf16
__global__ __launch_bounds__(256) void transpose_bf16(const float* __restrict__ in,
                                                      unsigned short* __restrict__ out,
                                                      int R, int C) {
    __shared__ float t[32][33];
    const int c0 = blockIdx.x * 32, r0 = blockIdx.y * 32;
    const int tx = threadIdx.x, ty = threadIdx.y;  // block (32,8)
#pragma unroll
    for (int i = 0; i < 4; i++)
        t[ty + 8 * i][tx] = in[(size_t)(r0 + ty + 8 * i) * C + c0 + tx];
    __syncthreads();
#pragma unroll
    for (int i = 0; i < 4; i++)
        out[(size_t)(c0 + ty + 8 * i) * R + r0 + tx] = f2b(t[tx][ty + 8 * i]);
}

// ---------------- LayerNorm: x[row][2048] f32 -> out bf16
__global__ __launch_bounds__(256) void ln_k(const float* __restrict__ x,
                                            const float* __restrict__ g,
                                            const float* __restrict__ bta,
                                            unsigned short* __restrict__ out) {
    const int row = blockIdx.x, tid = threadIdx.x;
    const float* xr = x + (size_t)row * DM;
    float4 v0 = *(const float4*)&xr[tid * 4];
    float4 v1 = *(const float4*)&xr[1024 + tid * 4];
    float s  = v0.x + v0.y + v0.z + v0.w + v1.x + v1.y + v1.z + v1.w;
    float ss = v0.x * v0.x + v0.y * v0.y + v0.z * v0.z + v0.w * v0.w
             + v1.x * v1.x + v1.y * v1.y + v1.z * v1.z + v1.w * v1.w;
#pragma unroll
    for (int o = 32; o; o >>= 1) { s += __shfl_down(s, o); ss += __shfl_down(ss, o); }
    __shared__ float red[8];
    const int w = tid >> 6, l = tid & 63;
    if (l == 0) { red[w] = s; red[4 + w] = ss; }
    __syncthreads();
    s  = red[0] + red[1] + red[2] + red[3];
    ss = red[4] + red[5] + red[6] + red[7];
    const float mu  = s * (1.0f / DM);
    const float var = ss * (1.0f / DM) - mu * mu;
    const float rst = rsqrtf(var + 1e-5f);
    float4 g0 = *(const float4*)&g[tid * 4];
    float4 b0 = *(const float4*)&bta[tid * 4];
    float4 g1 = *(const float4*)&g[1024 + tid * 4];
    float4 b1 = *(const float4*)&bta[1024 + tid * 4];
    ushort4 o0, o1;
    o0.x = f2b((v0.x - mu) * rst * g0.x + b0.x);
    o0.y = f2b((v0.y - mu) * rst * g0.y + b0.y);
    o0.z = f2b((v0.z - mu) * rst * g0.z + b0.z);
    o0.w = f2b((v0.w - mu) * rst * g0.w + b0.w);
    o1.x = f2b((v1.x - mu) * rst * g1.x + b1.x);
    o1.y = f2b((v1.y - mu) * rst * g1.y + b1.y);
    o1.z = f2b((v1.z - mu) * rst * g1.z + b1.z);
    o1.w = f2b((v1.w - mu) * rst * g1.w + b1.w);
    *(ushort4*)&out[(size_t)row * DM + tid * 4] = o0;
    *(ushort4*)&out[(size_t)row * DM + 1024 + tid * 4] = o1;
}

// ---------------- GEMM: C[M][N] = A[M][K]_bf16 @ Bt[N][K]_bf16 (+bias,+gelu,+res)
// m97 structure: 128x128 tile, BK=32, 4 waves * (4x4) 16x16x32 mfma, global_load_lds w=16
template <bool BIAS, bool GELU_, bool RES, bool OUTBF>
__global__ __launch_bounds__(256) void gemm_k(const unsigned short* __restrict__ A,
                                              const unsigned short* __restrict__ Bt,
                                              const float* __restrict__ bias,
                                              const float* __restrict__ res,
                                              void* __restrict__ outp,
                                              int M, int N, int K) {
    __shared__ unsigned short Al[128 * 32];
    __shared__ unsigned short Bl[128 * 32];
    const int tid = threadIdx.x, w = tid >> 6, l = tid & 63;
    const int n0 = blockIdx.x * 128, m0 = blockIdx.y * 128;
    const int wr = (w >> 1) * 64, wc = (w & 1) * 64;
    const int lr = l & 15, ko = (l >> 4) * 8;
    f32x4 acc[4][4] = {};

    const int srow = w * 32 + (l >> 2);
    const int skk  = (l & 3) * 8;
    const unsigned short* ga0 = A + (size_t)(m0 + srow) * K + skk;
    const unsigned short* ga1 = ga0 + (size_t)16 * K;
    const unsigned short* gb0 = Bt + (size_t)(n0 + srow) * K + skk;
    const unsigned short* gb1 = gb0 + (size_t)16 * K;
    unsigned short* la = &Al[w * 1024];
    unsigned short* lb = &Bl[w * 1024];
    const int nk = K >> 5;
    for (int kt = 0; kt < nk; ++kt) {
        GLDS16(ga0, la);
        GLDS16(ga1, la + 512);
        GLDS16(gb0, lb);
        GLDS16(gb1, lb + 512);
        ga0 += 32; ga1 += 32; gb0 += 32; gb1 += 32;
        __syncthreads();
        bf16x8 af[4], bv[4];
#pragma unroll
        for (int i = 0; i < 4; i++) af[i] = *(const bf16x8*)&Al[(wr + i * 16 + lr) * 32 + ko];
#pragma unroll
        for (int i = 0; i < 4; i++) bv[i] = *(const bf16x8*)&Bl[(wc + i * 16 + lr) * 32 + ko];
#pragma unroll
        for (int i = 0; i < 4; i++)
#pragma unroll
            for (int j = 0; j < 4; j++)
                acc[i][j] = __builtin_amdgcn_mfma_f32_16x16x32_bf16(af[i], bv[j], acc[i][j], 0, 0, 0);
        __syncthreads();
    }
    // epilogue: C/D map row=(l>>4)*4+r, col=l&15 (HW-verified)
#pragma unroll
    for (int j = 0; j < 4; j++) {
        const int col = n0 + wc + j * 16 + lr;
        const float bvv = BIAS ? bias[col] : 0.0f;
#pragma unroll
        for (int i = 0; i < 4; i++) {
#pragma unroll
            for (int r = 0; r < 4; r++) {
                const int row = m0 + wr + i * 16 + (l >> 4) * 4 + r;
                float v = acc[i][j][r] + bvv;
                if (GELU_) v = 0.5f * v * (1.0f + erff(v * 0.7071067811865476f));
                if (RES) v += res[(size_t)row * N + col];
                if (OUTBF) ((unsigned short*)outp)[(size_t)row * N + col] = f2b(v);
                else       ((float*)outp)[(size_t)row * N + col] = v;
            }
        }
    }
}

// ---------------- flash attention (causal), qkv bf16 [B*L][3*DM], out bf16 [B*L][DM]
// Uniform pairing: block handles q-tiles {bx, 31-bx} -> exactly 33 K-tile iters/block.
// Vt XOR-swizzled: element (d,key) at short-index d*64 + (key ^ 8*s(d)), s(d)=((d>>3)^d)&7.
//   write side: 16-way bank conflict -> 2-way; read side stays 2-way, 16B-aligned.
__global__ __launch_bounds__(256) void flash_attn_k(const unsigned short* __restrict__ qkv,
                                                    unsigned short* __restrict__ out) {
    __shared__ unsigned short Kl[64 * 136];   // K tile [key][d], padded stride 136
    __shared__ unsigned short Vt[128 * 64];   // V tile transposed [d][key], XOR-swizzled
    __shared__ unsigned short Pl[4][16 * 72]; // per-wave P [qrow][key], padded
    const int tid = threadIdx.x, w = tid >> 6, l = tid & 63;
    const int bh = blockIdx.y, b = bh >> 4, h = bh & 15;
    const int lr = l & 15, lg = l >> 4;
    const float sc = 0.08838834764831845f;  // 1/sqrt(128)
    const int NT = LSEQ / 64;               // 32

#pragma unroll 1
    for (int pi = 0; pi < 2; ++pi) {
        const int qt = (pi == 0) ? (int)blockIdx.x : (NT - 1 - (int)blockIdx.x);
        const int qw = qt * 64 + w * 16;

        bf16x8 qf[4];
        {
            const unsigned short* qb = qkv + (size_t)(b * LSEQ + qw + lr) * (3 * DM) + h * HDIM + lg * 8;
#pragma unroll
            for (int kc = 0; kc < 4; kc++) qf[kc] = *(const bf16x8*)(qb + kc * 32);
        }
        f32x4 O[8] = {};
        float m_run[4] = {-1e30f, -1e30f, -1e30f, -1e30f};
        float l_run[4] = {};

        for (int kt = 0; kt <= qt; ++kt) {
            const int k0 = kt * 64;
            // stage K row-major (padded), V transposed+swizzled. 64 rows x 16 chunks
#pragma unroll
            for (int i = 0; i < 4; i++) {
                const int seg = i * 256 + tid;       // 0..1023
                const int row = seg >> 4;            // 0..63
                const int c8  = (seg & 15) * 8;      // 0..120
                const unsigned short* src = qkv + (size_t)(b * LSEQ + k0 + row) * (3 * DM) + DM + h * HDIM + c8;
                *(uint4*)&Kl[row * 136 + c8] = *(const uint4*)src;
                unsigned short tmp[8];
                *(uint4*)tmp = *(const uint4*)(src + DM);
#pragma unroll
                for (int j = 0; j < 8; j++) {
                    const int d = c8 + j;
                    Vt[d * 64 + (row ^ ((((d >> 3) ^ d) & 7) << 3))] = tmp[j];
                }
            }
            __syncthreads();
            // S = Q K^T  (A=Q rows, B=K^T: lane reads Kl[key=st*16+lr][d])
            f32x4 S[4] = {};
#pragma unroll
            for (int st = 0; st < 4; ++st)
#pragma unroll
                for (int kc = 0; kc < 4; kc++) {
                    bf16x8 kb = *(const bf16x8*)&Kl[(st * 16 + lr) * 136 + kc * 32 + lg * 8];
                    S[st] = __builtin_amdgcn_mfma_f32_16x16x32_bf16(qf[kc], kb, S[st], 0, 0, 0);
                }
            const bool last = (kt == qt);
#pragma unroll
            for (int r = 0; r < 4; r++) {
                const int row = qw + lg * 4 + r;
                float s0 = S[0][r] * sc, s1 = S[1][r] * sc, s2 = S[2][r] * sc, s3 = S[3][r] * sc;
                if (last) {
                    if (k0 +  0 + lr > row) s0 = -1e30f;
                    if (k0 + 16 + lr > row) s1 = -1e30f;
                    if (k0 + 32 + lr > row) s2 = -1e30f;
                    if (k0 + 48 + lr > row) s3 = -1e30f;
                }
                float mt = fmaxf(fmaxf(s0, s1), fmaxf(s2, s3));
                mt = fmaxf(mt, __shfl_xor(mt, 1));
                mt = fmaxf(mt, __shfl_xor(mt, 2));
                mt = fmaxf(mt, __shfl_xor(mt, 4));
                mt = fmaxf(mt, __shfl_xor(mt, 8));
                const float mn = fmaxf(m_run[r], mt);
                const float al = __expf(m_run[r] - mn);
                m_run[r] = mn;
                float p0 = __expf(s0 - mn), p1 = __expf(s1 - mn), p2 = __expf(s2 - mn), p3 = __expf(s3 - mn);
                float ts = p0 + p1 + p2 + p3;
                ts += __shfl_xor(ts, 1);
                ts += __shfl_xor(ts, 2);
                ts += __shfl_xor(ts, 4);
                ts += __shfl_xor(ts, 8);
                l_run[r] = l_run[r] * al + ts;
#pragma unroll
                for (int c = 0; c < 8; c++) O[c][r] *= al;
                unsigned short* pr = &Pl[w][(lg * 4 + r) * 72 + lr];
                pr[0] = f2b(p0); pr[16] = f2b(p1); pr[32] = f2b(p2); pr[48] = f2b(p3);
            }
            // O += P @ V   (A=P[qrow][key], B read from swizzled Vt[d][key])
#pragma unroll
            for (int ks = 0; ks < 2; ++ks) {
                bf16x8 pa = *(const bf16x8*)&Pl[w][lr * 72 + ks * 32 + lg * 8];
#pragma unroll
                for (int c = 0; c < 8; c++) {
                    const int d = c * 16 + lr;
                    bf16x8 vb = *(const bf16x8*)&Vt[d * 64 + ((ks * 32 + lg * 8) ^ ((((d >> 3) ^ d) & 7) << 3))];
                    O[c] = __builtin_amdgcn_mfma_f32_16x16x32_bf16(pa, vb, O[c], 0, 0, 0);
                }
            }
            __syncthreads();
        }
#pragma unroll
        for (int r = 0; r < 4; r++) {
            const float inv = 1.0f / l_run[r];
            const size_t ro = (size_t)(b * LSEQ + qw + lg * 4 + r) * DM + h * HDIM;
#pragma unroll
            for (int c = 0; c < 8; c++) out[ro + c * 16 + lr] = f2b(O[c][r] * inv);
        }
    }
}

extern "C" void kernel_launch(void* const* d_in, const int* in_sizes, int n_in,
                              void* d_out, int out_size, void* d_ws, size_t ws_size,
                              hipStream_t stream) {
    const float* x     = (const float*)d_in[0];
    // d_in[1] = attention_mask (causal tril; hardcoded in flash kernel)
    const float* w_qkv = (const float*)d_in[2];
    const float* w_o   = (const float*)d_in[3];
    const float* g1    = (const float*)d_in[4];
    const float* bl1   = (const float*)d_in[5];
    const float* g2    = (const float*)d_in[6];
    const float* bl2   = (const float*)d_in[7];
    const float* w1    = (const float*)d_in[8];
    const float* b1    = (const float*)d_in[9];
    const float* w2    = (const float*)d_in[10];
    const float* b2    = (const float*)d_in[11];
    float* out = (float*)d_out;

    unsigned char* p = (unsigned char*)d_ws;
    unsigned short* wqkvT = (unsigned short*)p; p += (size_t)3 * DM * DM * 2;   // [6144][2048]
    unsigned short* woT   = (unsigned short*)p; p += (size_t)DM * DM * 2;       // [2048][2048]
    unsigned short* w1T   = (unsigned short*)p; p += (size_t)DFF * DM * 2;      // [8192][2048]
    unsigned short* w2T   = (unsigned short*)p; p += (size_t)DM * DFF * 2;      // [2048][8192]
    unsigned short* hbuf  = (unsigned short*)p; p += (size_t)NB * LSEQ * DM * 2;  // h / attn_out / h2
    unsigned short* big   = (unsigned short*)p; p += (size_t)NB * LSEQ * DFF * 2; // qkv then mlp hidden
    float* x2 = out;  // x2 lives in d_out; final GEMM reads it as res then overwrites in place

    const int R = NB * LSEQ;  // 4096
    dim3 tb(32, 8);
    transpose_bf16<<<dim3(3 * DM / 32, DM / 32), tb, 0, stream>>>(w_qkv, wqkvT, DM, 3 * DM);
    transpose_bf16<<<dim3(DM / 32, DM / 32), tb, 0, stream>>>(w_o, woT, DM, DM);
    transpose_bf16<<<dim3(DFF / 32, DM / 32), tb, 0, stream>>>(w1, w1T, DM, DFF);
    transpose_bf16<<<dim3(DM / 32, DFF / 32), tb, 0, stream>>>(w2, w2T, DFF, DM);

    ln_k<<<R, 256, 0, stream>>>(x, g1, bl1, hbuf);
    gemm_k<false, false, false, true><<<dim3(3 * DM / 128, R / 128), 256, 0, stream>>>(
        hbuf, wqkvT, nullptr, nullptr, big, R, 3 * DM, DM);
    flash_attn_k<<<dim3(LSEQ / 128, NB * NH), 256, 0, stream>>>(big, hbuf);
    gemm_k<false, false, true, false><<<dim3(DM / 128, R / 128), 256, 0, stream>>>(
        hbuf, woT, nullptr, x, x2, R, DM, DM);
    ln_k<<<R, 256, 0, stream>>>(x2, g2, bl2, hbuf);
    gemm_k<true, true, false, true><<<dim3(DFF / 128, R / 128), 256, 0, stream>>>(
        hbuf, w1T, b1, nullptr, big, R, DFF, DM);
    gemm_k<true, false, true, false><<<dim3(DM / 128, R / 128), 256, 0, stream>>>(
        big, w2T, b2, x2, out, R, DM, DFF);
}